// Round 5
// baseline (114.202 us; speedup 1.0000x reference)
//
#include <hip/hip_runtime.h>
#include <hip/hip_bf16.h>
#include <stdint.h>

#define Rdim 1023
#define BFR  4190208           // 64*64*1023

typedef __bf16 bf16;
typedef __bf16 bf16x8 __attribute__((ext_vector_type(8)));
typedef __bf16 bf16x4 __attribute__((ext_vector_type(4)));
typedef float  f32x4  __attribute__((ext_vector_type(4)));
typedef float  f32x16 __attribute__((ext_vector_type(16)));
typedef float  f32x4u __attribute__((ext_vector_type(4), aligned(4)));

__device__ __forceinline__ void async16(const void* g, void* l) {
    __builtin_amdgcn_global_load_lds(
        (const __attribute__((address_space(1))) void*)g,
        (__attribute__((address_space(3))) void*)l, 16, 0, 0);
}

// ---------------------------------------------------------------------------
// Fused prep kernel (unchanged — proven, near HBM floor).
// Swizzle: 16B chunk c of row m stored at chunk (c ^ (m&7)) within its
// 128B (8-chunk) window -> GEMM staging is a LINEAR copy, ds_read XORs.
// ---------------------------------------------------------------------------
__global__ __launch_bounds__(256) void k_prep(
    const float* __restrict__ x,
    const float* __restrict__ w0, const float* __restrict__ w1,
    const float* __restrict__ w2, const float* __restrict__ w3,
    const float* __restrict__ Dl, const float* __restrict__ Dr,
    const float* __restrict__ El, const float* __restrict__ Er,
    bf16* __restrict__ args, bf16* __restrict__ dpad,
    float* __restrict__ out)
{
    const int blk = blockIdx.x;
    const int t   = threadIdx.x;

    if (blk < 4096) {
        const int b = blk >> 6;
        float wr0[16], wr1[16], wr2[16], wr3[16];
#pragma unroll
        for (int l = 0; l < 16; ++l) {
            wr0[l] = w0[b*16 + l]; wr1[l] = w1[b*16 + l];
            wr2[l] = w2[b*16 + l]; wr3[l] = w3[b*16 + l];
        }
        const float* xb = x + ((size_t)(b*16)*64 + (blk & 63)) * (size_t)Rdim;
        float a0[4] = {}, a1[4] = {}, a2[4] = {}, a3[4] = {};
        if (t < 255) {
#pragma unroll
            for (int l = 0; l < 16; ++l) {
                f32x4u v = *(const f32x4u*)(xb + (size_t)l*(64*(size_t)Rdim) + t*4);
#pragma unroll
                for (int j = 0; j < 4; ++j) {
                    a0[j] += wr0[l]*v[j]; a1[j] += wr1[l]*v[j];
                    a2[j] += wr2[l]*v[j]; a3[j] += wr3[l]*v[j];
                }
            }
        } else {
#pragma unroll
            for (int l = 0; l < 16; ++l) {
                const float* p = xb + (size_t)l*(64*(size_t)Rdim) + 1020;
#pragma unroll
                for (int j = 0; j < 3; ++j) {
                    float v = p[j];
                    a0[j] += wr0[l]*v; a1[j] += wr1[l]*v;
                    a2[j] += wr2[l]*v; a3[j] += wr3[l]*v;
                }
            }
        }
        const int c   = t >> 1;
        const int S   = blk & 7;
        const int off = ((c ^ S) << 3) + ((t & 1) << 2);
        bf16x4 s0, s1, s2, s3;
#pragma unroll
        for (int j = 0; j < 4; ++j) {
            s0[j] = (bf16)a0[j]; s1[j] = (bf16)a1[j];
            s2[j] = (bf16)a2[j]; s3[j] = (bf16)a3[j];
        }
        *(bf16x4*)(args +            (size_t)blk*1024 + off) = s0;
        *(bf16x4*)(args + 4194304 +  (size_t)blk*1024 + off) = s1;
        bf16* c12 = args + 8388608 + (size_t)blk*2048;
        *(bf16x4*)(c12 + off)        = s2;
        *(bf16x4*)(c12 + 1024 + off) = s3;
    } else if (blk < 6144) {
        const int id = (blk - 4096)*256 + t;
        const float* src; int n, c, K; size_t base;
        if (id < 262144) {
            const int m2  = id >> 17;
            src = m2 ? Dr : Dl;
            const int rem = id & 131071;
            n = rem >> 7; c = rem & 127; K = 1024;
            base = m2 ? 1048576u : 0u;
        } else {
            const int rem = id - 262144;
            n = rem >> 8; c = rem & 255; K = 2048;
            base = 2097152u;
            src = (c < 128) ? El : Er;
        }
        const int cl = c & 127;
        float v[8] = {};
        if (n < Rdim) {
            const float* sp = src + (size_t)n*Rdim + cl*8;
            if (cl < 127) {
                f32x4u u0 = *(const f32x4u*)sp;
                f32x4u u1 = *(const f32x4u*)(sp + 4);
#pragma unroll
                for (int j = 0; j < 4; ++j) { v[j] = u0[j]; v[4+j] = u1[j]; }
            } else {
                f32x4u u0 = *(const f32x4u*)sp;
#pragma unroll
                for (int j = 0; j < 4; ++j) v[j] = u0[j];
                v[4] = sp[4]; v[5] = sp[5]; v[6] = sp[6];
            }
        }
        const int swc = c ^ (n & 7);
        bf16x8 s;
#pragma unroll
        for (int j = 0; j < 8; ++j) s[j] = (bf16)v[j];
        *(bf16x8*)(dpad + base + (size_t)n*K + swc*8) = s;
    } else {
        const int k = t >> 6, b2 = t & 63;
        const float* w = (k==0) ? w0 : (k==1) ? w1 : (k==2) ? w2 : w3;
        float s = 0.f, mx = -1e30f;
#pragma unroll
        for (int l = 0; l < 16; ++l) {
            float p = w[b2*16 + l];
            s += p * logf(p + 1e-12f);
            mx = fmaxf(mx, p);
        }
        out[3*(size_t)BFR +       k*64 + b2] = -s / logf(16.f);
        out[3*(size_t)BFR + 256 + k*64 + b2] = mx;
    }
}

// ---------------------------------------------------------------------------
// 128x256 MFMA GEMM with 32x32x16 bf16 MFMA (2382 TF class, +15% vs 16x16).
// 8 waves 2M x 4N: wave = 64 rows x 64 cols = 2x2 supertiles of 32x32.
// Per wave per K-tile(64): 16 ds_read_b128 + 16 MFMA (was 20 + 32).
// Pipeline identical to round 4: triple-buffered LDS (144 KiB), 2 phases
// per K-tile, stage kt+2 (A=2 + B=4 async16 units), counted vmcnt(6).
// grid = 384: per XCD 16 cons (K=2048, FIRST) + 16 car + 16 cdr (K=1024).
// ---------------------------------------------------------------------------
#define BAR()  do { __builtin_amdgcn_s_barrier(); __builtin_amdgcn_sched_barrier(0); } while(0)

// A frag (mi, ks): row = wm*64 + mi*32 + lr32, chunk = (ks*2 + lk2) ^ (lr32&7)
#define LDA(CA) do {                                                          \
    _Pragma("unroll") for (int mi = 0; mi < 2; ++mi)                          \
    _Pragma("unroll") for (int ks = 0; ks < 4; ++ks)                          \
        af[mi*4+ks] = *(const bf16x8*)((CA) + (wm*64 + mi*32 + lr32)*128      \
                                            + (((ks*2 + lk2) ^ lm)<<4));      \
} while(0)

// B frag (ks) for fixed NJ: row = wn*64 + NJ*32 + lr32
#define LDB(CB, NJ) do {                                                      \
    _Pragma("unroll") for (int ks = 0; ks < 4; ++ks)                          \
        bfr[ks] = *(const bf16x8*)((CB) + (wn*64 + (NJ)*32 + lr32)*128        \
                                        + (((ks*2 + lk2) ^ lm)<<4));          \
} while(0)

#define MMQ(NJ) do {                                                          \
    __builtin_amdgcn_s_setprio(1);                                            \
    _Pragma("unroll") for (int ks = 0; ks < 4; ++ks)                          \
    _Pragma("unroll") for (int mi = 0; mi < 2; ++mi)                          \
        acc[mi][NJ] = __builtin_amdgcn_mfma_f32_32x32x16_bf16(                \
            af[mi*4+ks], bfr[ks], acc[mi][NJ], 0, 0, 0);                      \
    __builtin_amdgcn_s_setprio(0);                                            \
} while(0)

#define STAGE_A2(SA, kt) do {                                                 \
    const char* _g = AgT + (size_t)(kt)*128;                                  \
    char* _l = (SA) + wave*1024;                                              \
    async16(_g, _l); async16(_g + 64*(size_t)AstB, _l + 8192);                \
} while(0)

#define STAGE_B1(SB, kt) do {                                                 \
    async16(BgT + (size_t)(kt)*128, (SB) + wave*1024);                        \
} while(0)

#define STAGE_B3(SB, kt) do {                                                 \
    const char* _g = BgT + (size_t)(kt)*128;                                  \
    char* _l = (SB) + wave*1024;                                              \
    async16(_g +  64*(size_t)AstB, _l + 8192);                                \
    async16(_g + 128*(size_t)AstB, _l + 16384);                               \
    async16(_g + 192*(size_t)AstB, _l + 24576);                               \
} while(0)

__global__ __launch_bounds__(512, 2) void k_gemm32(
    const bf16* __restrict__ args, const bf16* __restrict__ dpad,
    const float* __restrict__ root_filler, const float* __restrict__ root_role,
    float* __restrict__ out)
{
    __shared__ char lds[147456];      // 144 KiB

    const int bid = blockIdx.x;
    const int xcd = bid & 7, idx = bid >> 3;
    int job, tile;
    if (idx < 16)      { job = 2; tile = xcd*16 + idx;      }  // cons FIRST (1-unit)
    else if (idx < 32) { job = 0; tile = xcd*16 + idx - 16; }  // car
    else               { job = 1; tile = xcd*16 + idx - 32; }  // cdr
    const int mt = tile >> 2;
    const int nt = tile & 3;

    const bf16* Ab = (job==0) ? args : (job==1) ? args+4194304 : args+8388608;
    const bf16* Bb = (job==0) ? dpad : (job==1) ? dpad+1048576 : dpad+2097152;
    const int AstB = (job < 2) ? 2048 : 4096;      // row stride BYTES (A and B)
    const int nkt  = (job < 2) ? 16 : 32;          // K/64

    const int tid  = threadIdx.x;
    const int wave = tid >> 6, lane = tid & 63;
    const int wm   = wave >> 2, wn = wave & 3;     // 2M x 4N
    const int lr32 = lane & 31, lk2 = lane >> 5, lm = lane & 7;

    const char* AgT = (const char*)Ab + (size_t)(mt*128 + (tid>>3))*AstB + (tid&7)*16;
    const char* BgT = (const char*)Bb + (size_t)(nt*256 + (tid>>3))*AstB + (tid&7)*16;

    f32x16 acc[2][2] = {};
    bf16x8 af[8], bfr[4];

    // prologue: kt0 -> buf0, kt1 -> buf1 (6 units each); wait kt0 landed
    STAGE_A2(lds,         0); STAGE_B1(lds + 49152, 0); STAGE_B3(lds + 49152, 0);
    STAGE_A2(lds + 16384, 1); STAGE_B1(lds + 81920, 1); STAGE_B3(lds + 81920, 1);
    asm volatile("s_waitcnt vmcnt(6)" ::: "memory");
    BAR();

    int cb = 0;
    for (int kt = 0; kt < nkt; ++kt) {
        char* cA = lds + cb*16384;
        char* cB = lds + 49152 + cb*32768;
        int sb = cb + 2; if (sb >= 3) sb -= 3;
        char* sA = lds + sb*16384;
        char* sB = lds + 49152 + sb*32768;
        const bool st = (kt + 2 < nkt);
        // P1: read A(8) + B nj=0 (4); stage 3 units of kt+2
        LDA(cA); LDB(cB, 0);
        if (st) { STAGE_A2(sA, kt+2); STAGE_B1(sB, kt+2); }
        BAR();
        MMQ(0);
        BAR();
        // P2: read B nj=1 (4); stage remaining 3 units; counted vmcnt
        LDB(cB, 1);
        if (st) STAGE_B3(sB, kt+2);
        BAR();
        MMQ(1);
        if (st)                { asm volatile("s_waitcnt vmcnt(6)" ::: "memory"); }
        else if (kt == nkt-2)  { asm volatile("s_waitcnt vmcnt(0)" ::: "memory"); }
        BAR();
        cb = cb + 1; if (cb == 3) cb = 0;
    }

    // epilogue: 32x32 C/D: col = lane&31, row = (q&3) + 8*(q>>2) + 4*(lane>>5)
    float* outp = out + (size_t)job * BFR;
#pragma unroll
    for (int mi = 0; mi < 2; ++mi) {
        const int gm0 = mt*128 + wm*64 + mi*32 + lk2*4;
#pragma unroll
        for (int nj = 0; nj < 2; ++nj) {
            const int gn = nt*256 + wn*64 + nj*32 + lr32;
            if (gn < Rdim) {
                const float rr = (job == 2) ? root_role[gn] : 0.f;
#pragma unroll
                for (int q = 0; q < 16; ++q) {
                    const int gm = gm0 + (q & 3) + 8*(q >> 2);
                    float v = acc[mi][nj][q];
                    if (job == 2) v += root_filler[gm] * rr;
                    outp[(size_t)gm*Rdim + gn] = v;
                }
            }
        }
    }
}

// ---------------------------------------------------------------------------
extern "C" void kernel_launch(void* const* d_in, const int* in_sizes, int n_in,
                              void* d_out, int out_size, void* d_ws, size_t ws_size,
                              hipStream_t stream)
{
    const float* x           = (const float*)d_in[0];
    const float* car_w       = (const float*)d_in[1];
    const float* cdr_w       = (const float*)d_in[2];
    const float* cons1_w     = (const float*)d_in[3];
    const float* cons2_w     = (const float*)d_in[4];
    const float* root_filler = (const float*)d_in[5];
    const float* Dl          = (const float*)d_in[6];
    const float* Dr          = (const float*)d_in[7];
    const float* El          = (const float*)d_in[8];
    const float* Er          = (const float*)d_in[9];
    const float* root_role   = (const float*)d_in[10];
    float* out = (float*)d_out;

    bf16* args = (bf16*)d_ws;                 // 33.5 MB
    bf16* dpad = args + 16777216;             //  8.4 MB

    k_prep  <<<dim3(6145), dim3(256), 0, stream>>>(
        x, car_w, cdr_w, cons1_w, cons2_w, Dl, Dr, El, Er, args, dpad, out);
    k_gemm32<<<dim3(384),  dim3(512), 0, stream>>>(
        args, dpad, root_filler, root_role, out);
}

// Round 6
// 110.283 us; speedup vs baseline: 1.0355x; 1.0355x over previous
//
#include <hip/hip_runtime.h>
#include <hip/hip_bf16.h>
#include <stdint.h>

#define Rdim 1023
#define BFR  4190208           // 64*64*1023

typedef __bf16 bf16;
typedef __bf16 bf16x8 __attribute__((ext_vector_type(8)));
typedef __bf16 bf16x4 __attribute__((ext_vector_type(4)));
typedef float  f32x4  __attribute__((ext_vector_type(4)));
typedef float  f32x4u __attribute__((ext_vector_type(4), aligned(4)));

__device__ __forceinline__ void async16(const void* g, void* l) {
    __builtin_amdgcn_global_load_lds(
        (const __attribute__((address_space(1))) void*)g,
        (__attribute__((address_space(3))) void*)l, 16, 0, 0);
}

// ---------------------------------------------------------------------------
// Fused prep kernel (unchanged — proven, near HBM floor).
// Swizzle: 16B chunk c of row m stored at chunk (c ^ (m&7)) within its
// 128B (8-chunk) window -> GEMM staging is a LINEAR copy, ds_read XORs.
// ---------------------------------------------------------------------------
__global__ __launch_bounds__(256) void k_prep(
    const float* __restrict__ x,
    const float* __restrict__ w0, const float* __restrict__ w1,
    const float* __restrict__ w2, const float* __restrict__ w3,
    const float* __restrict__ Dl, const float* __restrict__ Dr,
    const float* __restrict__ El, const float* __restrict__ Er,
    bf16* __restrict__ args, bf16* __restrict__ dpad,
    float* __restrict__ out)
{
    const int blk = blockIdx.x;
    const int t   = threadIdx.x;

    if (blk < 4096) {
        const int b = blk >> 6;
        float wr0[16], wr1[16], wr2[16], wr3[16];
#pragma unroll
        for (int l = 0; l < 16; ++l) {
            wr0[l] = w0[b*16 + l]; wr1[l] = w1[b*16 + l];
            wr2[l] = w2[b*16 + l]; wr3[l] = w3[b*16 + l];
        }
        const float* xb = x + ((size_t)(b*16)*64 + (blk & 63)) * (size_t)Rdim;
        float a0[4] = {}, a1[4] = {}, a2[4] = {}, a3[4] = {};
        if (t < 255) {
#pragma unroll
            for (int l = 0; l < 16; ++l) {
                f32x4u v = *(const f32x4u*)(xb + (size_t)l*(64*(size_t)Rdim) + t*4);
#pragma unroll
                for (int j = 0; j < 4; ++j) {
                    a0[j] += wr0[l]*v[j]; a1[j] += wr1[l]*v[j];
                    a2[j] += wr2[l]*v[j]; a3[j] += wr3[l]*v[j];
                }
            }
        } else {
#pragma unroll
            for (int l = 0; l < 16; ++l) {
                const float* p = xb + (size_t)l*(64*(size_t)Rdim) + 1020;
#pragma unroll
                for (int j = 0; j < 3; ++j) {
                    float v = p[j];
                    a0[j] += wr0[l]*v; a1[j] += wr1[l]*v;
                    a2[j] += wr2[l]*v; a3[j] += wr3[l]*v;
                }
            }
        }
        const int c   = t >> 1;
        const int S   = blk & 7;
        const int off = ((c ^ S) << 3) + ((t & 1) << 2);
        bf16x4 s0, s1, s2, s3;
#pragma unroll
        for (int j = 0; j < 4; ++j) {
            s0[j] = (bf16)a0[j]; s1[j] = (bf16)a1[j];
            s2[j] = (bf16)a2[j]; s3[j] = (bf16)a3[j];
        }
        *(bf16x4*)(args +            (size_t)blk*1024 + off) = s0;
        *(bf16x4*)(args + 4194304 +  (size_t)blk*1024 + off) = s1;
        bf16* c12 = args + 8388608 + (size_t)blk*2048;
        *(bf16x4*)(c12 + off)        = s2;
        *(bf16x4*)(c12 + 1024 + off) = s3;
    } else if (blk < 6144) {
        const int id = (blk - 4096)*256 + t;
        const float* src; int n, c, K; size_t base;
        if (id < 262144) {
            const int m2  = id >> 17;
            src = m2 ? Dr : Dl;
            const int rem = id & 131071;
            n = rem >> 7; c = rem & 127; K = 1024;
            base = m2 ? 1048576u : 0u;
        } else {
            const int rem = id - 262144;
            n = rem >> 8; c = rem & 255; K = 2048;
            base = 2097152u;
            src = (c < 128) ? El : Er;
        }
        const int cl = c & 127;
        float v[8] = {};
        if (n < Rdim) {
            const float* sp = src + (size_t)n*Rdim + cl*8;
            if (cl < 127) {
                f32x4u u0 = *(const f32x4u*)sp;
                f32x4u u1 = *(const f32x4u*)(sp + 4);
#pragma unroll
                for (int j = 0; j < 4; ++j) { v[j] = u0[j]; v[4+j] = u1[j]; }
            } else {
                f32x4u u0 = *(const f32x4u*)sp;
#pragma unroll
                for (int j = 0; j < 4; ++j) v[j] = u0[j];
                v[4] = sp[4]; v[5] = sp[5]; v[6] = sp[6];
            }
        }
        const int swc = c ^ (n & 7);
        bf16x8 s;
#pragma unroll
        for (int j = 0; j < 8; ++j) s[j] = (bf16)v[j];
        *(bf16x8*)(dpad + base + (size_t)n*K + swc*8) = s;
    } else {
        const int k = t >> 6, b2 = t & 63;
        const float* w = (k==0) ? w0 : (k==1) ? w1 : (k==2) ? w2 : w3;
        float s = 0.f, mx = -1e30f;
#pragma unroll
        for (int l = 0; l < 16; ++l) {
            float p = w[b2*16 + l];
            s += p * logf(p + 1e-12f);
            mx = fmaxf(mx, p);
        }
        out[3*(size_t)BFR +       k*64 + b2] = -s / logf(16.f);
        out[3*(size_t)BFR + 256 + k*64 + b2] = mx;
    }
}

// ---------------------------------------------------------------------------
// 128x256 MFMA GEMM: 16x16x32 MFMA (r4-proven ILP) + 64x64 wave tiles
// (r5-proven minimal LDS frag traffic: 128 KB/CU/K-tile vs r4's 160 KB).
// 8 waves 2M x 4N; per wave per K-tile: 16 ds_read_b128 + 32 MFMA in two
// 16-MFMA clusters, 8 independent acc chains each (ks-chains depth 2).
// Pipeline identical to r4/r5: triple-buffered LDS (144 KiB), 2 phases per
// K-tile, stage kt+2 (A=2 + B=4 async16 units), counted vmcnt(6).
// grid = 384: per XCD 16 cons (K=2048, FIRST) + 16 car + 16 cdr (K=1024).
// ---------------------------------------------------------------------------
#define BAR()  do { __builtin_amdgcn_s_barrier(); __builtin_amdgcn_sched_barrier(0); } while(0)

// A frags: row = wm*64 + mi*16 + lr, chunk = (ks*4 + lk) ^ (lr&7)
#define LDA(CA) do {                                                          \
    _Pragma("unroll") for (int mi = 0; mi < 4; ++mi)                          \
    _Pragma("unroll") for (int ks = 0; ks < 2; ++ks)                          \
        af[mi*2+ks] = *(const bf16x8*)((CA) + (wm*64 + mi*16 + lr)*128        \
                                            + (((ks*4 + lk) ^ lm)<<4));      \
} while(0)

// B frags for col-half JH: row = wn*64 + (JH*2+j2)*16 + lr
#define LDB(CB, JH) do {                                                      \
    _Pragma("unroll") for (int j2 = 0; j2 < 2; ++j2)                          \
    _Pragma("unroll") for (int ks = 0; ks < 2; ++ks)                          \
        bfr[j2*2+ks] = *(const bf16x8*)((CB) + (wn*64 + ((JH)*2+j2)*16 + lr)*128 \
                                             + (((ks*4 + lk) ^ lm)<<4));     \
} while(0)

#define MMQ(JH) do {                                                          \
    __builtin_amdgcn_s_setprio(1);                                            \
    _Pragma("unroll") for (int ks = 0; ks < 2; ++ks)                          \
    _Pragma("unroll") for (int mi = 0; mi < 4; ++mi)                          \
    _Pragma("unroll") for (int j2 = 0; j2 < 2; ++j2)                          \
        acc[mi][(JH)*2+j2] = __builtin_amdgcn_mfma_f32_16x16x32_bf16(         \
            af[mi*2+ks], bfr[j2*2+ks], acc[mi][(JH)*2+j2], 0, 0, 0);          \
    __builtin_amdgcn_s_setprio(0);                                            \
} while(0)

#define STAGE_A2(SA, kt) do {                                                 \
    const char* _g = AgT + (size_t)(kt)*128;                                  \
    char* _l = (SA) + wave*1024;                                              \
    async16(_g, _l); async16(_g + 64*(size_t)AstB, _l + 8192);                \
} while(0)

#define STAGE_B1(SB, kt) do {                                                 \
    async16(BgT + (size_t)(kt)*128, (SB) + wave*1024);                        \
} while(0)

#define STAGE_B3(SB, kt) do {                                                 \
    const char* _g = BgT + (size_t)(kt)*128;                                  \
    char* _l = (SB) + wave*1024;                                              \
    async16(_g +  64*(size_t)AstB, _l + 8192);                                \
    async16(_g + 128*(size_t)AstB, _l + 16384);                               \
    async16(_g + 192*(size_t)AstB, _l + 24576);                               \
} while(0)

__global__ __launch_bounds__(512, 2) void k_gemm64(
    const bf16* __restrict__ args, const bf16* __restrict__ dpad,
    const float* __restrict__ root_filler, const float* __restrict__ root_role,
    float* __restrict__ out)
{
    __shared__ char lds[147456];      // 144 KiB

    const int bid = blockIdx.x;
    const int xcd = bid & 7, idx = bid >> 3;
    int job, tile;
    if (idx < 16)      { job = 2; tile = xcd*16 + idx;      }  // cons FIRST (1-unit)
    else if (idx < 32) { job = 0; tile = xcd*16 + idx - 16; }  // car
    else               { job = 1; tile = xcd*16 + idx - 32; }  // cdr
    const int mt = tile >> 2;
    const int nt = tile & 3;

    const bf16* Ab = (job==0) ? args : (job==1) ? args+4194304 : args+8388608;
    const bf16* Bb = (job==0) ? dpad : (job==1) ? dpad+1048576 : dpad+2097152;
    const int AstB = (job < 2) ? 2048 : 4096;      // row stride BYTES (A and B)
    const int nkt  = (job < 2) ? 16 : 32;          // K/64

    const int tid  = threadIdx.x;
    const int wave = tid >> 6, lane = tid & 63;
    const int wm   = wave >> 2, wn = wave & 3;     // 2M x 4N, wave = 64x64
    const int lr   = lane & 15, lk = lane >> 4, lm = lane & 7;

    const char* AgT = (const char*)Ab + (size_t)(mt*128 + (tid>>3))*AstB + (tid&7)*16;
    const char* BgT = (const char*)Bb + (size_t)(nt*256 + (tid>>3))*AstB + (tid&7)*16;

    f32x4 acc[4][4] = {};
    bf16x8 af[8], bfr[4];

    // prologue: kt0 -> buf0, kt1 -> buf1 (6 units each); wait kt0 landed
    STAGE_A2(lds,         0); STAGE_B1(lds + 49152, 0); STAGE_B3(lds + 49152, 0);
    STAGE_A2(lds + 16384, 1); STAGE_B1(lds + 81920, 1); STAGE_B3(lds + 81920, 1);
    asm volatile("s_waitcnt vmcnt(6)" ::: "memory");
    BAR();

    int cb = 0;
    for (int kt = 0; kt < nkt; ++kt) {
        char* cA = lds + cb*16384;
        char* cB = lds + 49152 + cb*32768;
        int sb = cb + 2; if (sb >= 3) sb -= 3;
        char* sA = lds + sb*16384;
        char* sB = lds + 49152 + sb*32768;
        const bool st = (kt + 2 < nkt);
        // P1: read A(8) + B cols 0-31 (4); stage 3 units of kt+2
        LDA(cA); LDB(cB, 0);
        if (st) { STAGE_A2(sA, kt+2); STAGE_B1(sB, kt+2); }
        BAR();
        MMQ(0);
        BAR();
        // P2: read B cols 32-63 (4); stage remaining 3 units; counted vmcnt
        LDB(cB, 1);
        if (st) STAGE_B3(sB, kt+2);
        BAR();
        MMQ(1);
        if (st)                { asm volatile("s_waitcnt vmcnt(6)" ::: "memory"); }
        else if (kt == nkt-2)  { asm volatile("s_waitcnt vmcnt(0)" ::: "memory"); }
        BAR();
        cb = cb + 1; if (cb == 3) cb = 0;
    }

    // epilogue: 16x16 C/D: col = lane&15, row = (lane>>4)*4 + q
    float* outp = out + (size_t)job * BFR;
#pragma unroll
    for (int mi = 0; mi < 4; ++mi) {
        const int gm0 = mt*128 + wm*64 + mi*16 + lk*4;
#pragma unroll
        for (int j = 0; j < 4; ++j) {
            const int gn = nt*256 + wn*64 + j*16 + lr;
            if (gn < Rdim) {
                const float rr = (job == 2) ? root_role[gn] : 0.f;
#pragma unroll
                for (int q = 0; q < 4; ++q) {
                    const int gm = gm0 + q;
                    float v = acc[mi][j][q];
                    if (job == 2) v += root_filler[gm] * rr;
                    outp[(size_t)gm*Rdim + gn] = v;
                }
            }
        }
    }
}

// ---------------------------------------------------------------------------
extern "C" void kernel_launch(void* const* d_in, const int* in_sizes, int n_in,
                              void* d_out, int out_size, void* d_ws, size_t ws_size,
                              hipStream_t stream)
{
    const float* x           = (const float*)d_in[0];
    const float* car_w       = (const float*)d_in[1];
    const float* cdr_w       = (const float*)d_in[2];
    const float* cons1_w     = (const float*)d_in[3];
    const float* cons2_w     = (const float*)d_in[4];
    const float* root_filler = (const float*)d_in[5];
    const float* Dl          = (const float*)d_in[6];
    const float* Dr          = (const float*)d_in[7];
    const float* El          = (const float*)d_in[8];
    const float* Er          = (const float*)d_in[9];
    const float* root_role   = (const float*)d_in[10];
    float* out = (float*)d_out;

    bf16* args = (bf16*)d_ws;                 // 33.5 MB
    bf16* dpad = args + 16777216;             //  8.4 MB

    k_prep  <<<dim3(6145), dim3(256), 0, stream>>>(
        x, car_w, cdr_w, cons1_w, cons2_w, Dl, Dr, El, Er, args, dpad, out);
    k_gemm64<<<dim3(384),  dim3(512), 0, stream>>>(
        args, dpad, root_filler, root_role, out);
}

// Round 7
// 108.151 us; speedup vs baseline: 1.0560x; 1.0197x over previous
//
#include <hip/hip_runtime.h>
#include <hip/hip_bf16.h>
#include <stdint.h>

#define Rdim 1023
#define BFR  4190208           // 64*64*1023

typedef __bf16 bf16;
typedef __bf16 bf16x8 __attribute__((ext_vector_type(8)));
typedef __bf16 bf16x4 __attribute__((ext_vector_type(4)));
typedef float  f32x4  __attribute__((ext_vector_type(4)));
typedef float  f32x4u __attribute__((ext_vector_type(4), aligned(4)));

__device__ __forceinline__ void async16(const void* g, void* l) {
    __builtin_amdgcn_global_load_lds(
        (const __attribute__((address_space(1))) void*)g,
        (__attribute__((address_space(3))) void*)l, 16, 0, 0);
}

// ---------------------------------------------------------------------------
// Fused prep kernel (unchanged — proven, near HBM floor).
// Swizzle: 16B chunk c of row m stored at chunk (c ^ (m&7)) within its
// 128B (8-chunk) window -> GEMM staging is a LINEAR copy, ds_read XORs.
// ---------------------------------------------------------------------------
__global__ __launch_bounds__(256) void k_prep(
    const float* __restrict__ x,
    const float* __restrict__ w0, const float* __restrict__ w1,
    const float* __restrict__ w2, const float* __restrict__ w3,
    const float* __restrict__ Dl, const float* __restrict__ Dr,
    const float* __restrict__ El, const float* __restrict__ Er,
    bf16* __restrict__ args, bf16* __restrict__ dpad,
    float* __restrict__ out)
{
    const int blk = blockIdx.x;
    const int t   = threadIdx.x;

    if (blk < 4096) {
        const int b = blk >> 6;
        float wr0[16], wr1[16], wr2[16], wr3[16];
#pragma unroll
        for (int l = 0; l < 16; ++l) {
            wr0[l] = w0[b*16 + l]; wr1[l] = w1[b*16 + l];
            wr2[l] = w2[b*16 + l]; wr3[l] = w3[b*16 + l];
        }
        const float* xb = x + ((size_t)(b*16)*64 + (blk & 63)) * (size_t)Rdim;
        float a0[4] = {}, a1[4] = {}, a2[4] = {}, a3[4] = {};
        if (t < 255) {
#pragma unroll
            for (int l = 0; l < 16; ++l) {
                f32x4u v = *(const f32x4u*)(xb + (size_t)l*(64*(size_t)Rdim) + t*4);
#pragma unroll
                for (int j = 0; j < 4; ++j) {
                    a0[j] += wr0[l]*v[j]; a1[j] += wr1[l]*v[j];
                    a2[j] += wr2[l]*v[j]; a3[j] += wr3[l]*v[j];
                }
            }
        } else {
#pragma unroll
            for (int l = 0; l < 16; ++l) {
                const float* p = xb + (size_t)l*(64*(size_t)Rdim) + 1020;
#pragma unroll
                for (int j = 0; j < 3; ++j) {
                    float v = p[j];
                    a0[j] += wr0[l]*v; a1[j] += wr1[l]*v;
                    a2[j] += wr2[l]*v; a3[j] += wr3[l]*v;
                }
            }
        }
        const int c   = t >> 1;
        const int S   = blk & 7;
        const int off = ((c ^ S) << 3) + ((t & 1) << 2);
        bf16x4 s0, s1, s2, s3;
#pragma unroll
        for (int j = 0; j < 4; ++j) {
            s0[j] = (bf16)a0[j]; s1[j] = (bf16)a1[j];
            s2[j] = (bf16)a2[j]; s3[j] = (bf16)a3[j];
        }
        *(bf16x4*)(args +            (size_t)blk*1024 + off) = s0;
        *(bf16x4*)(args + 4194304 +  (size_t)blk*1024 + off) = s1;
        bf16* c12 = args + 8388608 + (size_t)blk*2048;
        *(bf16x4*)(c12 + off)        = s2;
        *(bf16x4*)(c12 + 1024 + off) = s3;
    } else if (blk < 6144) {
        const int id = (blk - 4096)*256 + t;
        const float* src; int n, c, K; size_t base;
        if (id < 262144) {
            const int m2  = id >> 17;
            src = m2 ? Dr : Dl;
            const int rem = id & 131071;
            n = rem >> 7; c = rem & 127; K = 1024;
            base = m2 ? 1048576u : 0u;
        } else {
            const int rem = id - 262144;
            n = rem >> 8; c = rem & 255; K = 2048;
            base = 2097152u;
            src = (c < 128) ? El : Er;
        }
        const int cl = c & 127;
        float v[8] = {};
        if (n < Rdim) {
            const float* sp = src + (size_t)n*Rdim + cl*8;
            if (cl < 127) {
                f32x4u u0 = *(const f32x4u*)sp;
                f32x4u u1 = *(const f32x4u*)(sp + 4);
#pragma unroll
                for (int j = 0; j < 4; ++j) { v[j] = u0[j]; v[4+j] = u1[j]; }
            } else {
                f32x4u u0 = *(const f32x4u*)sp;
#pragma unroll
                for (int j = 0; j < 4; ++j) v[j] = u0[j];
                v[4] = sp[4]; v[5] = sp[5]; v[6] = sp[6];
            }
        }
        const int swc = c ^ (n & 7);
        bf16x8 s;
#pragma unroll
        for (int j = 0; j < 8; ++j) s[j] = (bf16)v[j];
        *(bf16x8*)(dpad + base + (size_t)n*K + swc*8) = s;
    } else {
        const int k = t >> 6, b2 = t & 63;
        const float* w = (k==0) ? w0 : (k==1) ? w1 : (k==2) ? w2 : w3;
        float s = 0.f, mx = -1e30f;
#pragma unroll
        for (int l = 0; l < 16; ++l) {
            float p = w[b2*16 + l];
            s += p * logf(p + 1e-12f);
            mx = fmaxf(mx, p);
        }
        out[3*(size_t)BFR +       k*64 + b2] = -s / logf(16.f);
        out[3*(size_t)BFR + 256 + k*64 + b2] = mx;
    }
}

// ---------------------------------------------------------------------------
// 128x256 MFMA GEMM: 16x16x32, 8 waves of 64x64 (2M x 4N), triple-buffered
// LDS, ONE phase / ONE barrier per K-tile (was 4 barriers).
// Invariants: buf[kt] validated by prior iter's vmcnt(6)+BAR (6 outstanding
// = kt+1's units exactly); staging into sb=(kt-1)%3 safe since its readers
// finished before the iter-(kt-1) BAR (ds_reads drain before MFMA lgkmcnt).
// Per wave per K-tile: 16 ds_read_b128 + 6 global_load_lds + 32 MFMA
// (16 independent chains, depth 2). MFMA-bound: 1024 cyc MFMA vs 384 LDS.
// grid = 384: per XCD 16 cons (K=2048, FIRST) + 16 car + 16 cdr (K=1024).
// ---------------------------------------------------------------------------
#define BAR()  do { __builtin_amdgcn_s_barrier(); __builtin_amdgcn_sched_barrier(0); } while(0)

// A frags: row = wm*64 + mi*16 + lr, chunk = (ks*4 + lk) ^ (lr&7)
#define LDA(CA) do {                                                          \
    _Pragma("unroll") for (int mi = 0; mi < 4; ++mi)                          \
    _Pragma("unroll") for (int ks = 0; ks < 2; ++ks)                          \
        af[mi*2+ks] = *(const bf16x8*)((CA) + (wm*64 + mi*16 + lr)*128        \
                                            + (((ks*4 + lk) ^ lm)<<4));      \
} while(0)

// B frags: row = wn*64 + j*16 + lr (all 8)
#define LDB(CB) do {                                                          \
    _Pragma("unroll") for (int j2 = 0; j2 < 4; ++j2)                          \
    _Pragma("unroll") for (int ks = 0; ks < 2; ++ks)                          \
        bfr[j2*2+ks] = *(const bf16x8*)((CB) + (wn*64 + j2*16 + lr)*128       \
                                             + (((ks*4 + lk) ^ lm)<<4));     \
} while(0)

#define MMQ_ALL() do {                                                        \
    __builtin_amdgcn_s_setprio(1);                                            \
    _Pragma("unroll") for (int ks = 0; ks < 2; ++ks)                          \
    _Pragma("unroll") for (int mi = 0; mi < 4; ++mi)                          \
    _Pragma("unroll") for (int j2 = 0; j2 < 4; ++j2)                          \
        acc[mi][j2] = __builtin_amdgcn_mfma_f32_16x16x32_bf16(                \
            af[mi*2+ks], bfr[j2*2+ks], acc[mi][j2], 0, 0, 0);                 \
    __builtin_amdgcn_s_setprio(0);                                            \
} while(0)

#define STAGE_A2(SA, kt) do {                                                 \
    const char* _g = AgT + (size_t)(kt)*128;                                  \
    char* _l = (SA) + wave*1024;                                              \
    async16(_g, _l); async16(_g + 64*(size_t)AstB, _l + 8192);                \
} while(0)

#define STAGE_B4(SB, kt) do {                                                 \
    const char* _g = BgT + (size_t)(kt)*128;                                  \
    char* _l = (SB) + wave*1024;                                              \
    async16(_g, _l);                                                          \
    async16(_g +  64*(size_t)AstB, _l + 8192);                                \
    async16(_g + 128*(size_t)AstB, _l + 16384);                               \
    async16(_g + 192*(size_t)AstB, _l + 24576);                               \
} while(0)

__global__ __launch_bounds__(512, 2) void k_gemm1p(
    const bf16* __restrict__ args, const bf16* __restrict__ dpad,
    const float* __restrict__ root_filler, const float* __restrict__ root_role,
    float* __restrict__ out)
{
    __shared__ char lds[147456];      // 144 KiB

    const int bid = blockIdx.x;
    const int xcd = bid & 7, idx = bid >> 3;
    int job, tile;
    if (idx < 16)      { job = 2; tile = xcd*16 + idx;      }  // cons FIRST (1-unit)
    else if (idx < 32) { job = 0; tile = xcd*16 + idx - 16; }  // car
    else               { job = 1; tile = xcd*16 + idx - 32; }  // cdr
    const int mt = tile >> 2;
    const int nt = tile & 3;

    const bf16* Ab = (job==0) ? args : (job==1) ? args+4194304 : args+8388608;
    const bf16* Bb = (job==0) ? dpad : (job==1) ? dpad+1048576 : dpad+2097152;
    const int AstB = (job < 2) ? 2048 : 4096;      // row stride BYTES (A and B)
    const int nkt  = (job < 2) ? 16 : 32;          // K/64

    const int tid  = threadIdx.x;
    const int wave = tid >> 6, lane = tid & 63;
    const int wm   = wave >> 2, wn = wave & 3;     // 2M x 4N, wave = 64x64
    const int lr   = lane & 15, lk = lane >> 4, lm = lane & 7;

    const char* AgT = (const char*)Ab + (size_t)(mt*128 + (tid>>3))*AstB + (tid&7)*16;
    const char* BgT = (const char*)Bb + (size_t)(nt*256 + (tid>>3))*AstB + (tid&7)*16;

    f32x4 acc[4][4] = {};
    bf16x8 af[8], bfr[8];

    // prologue: kt0 -> buf0, kt1 -> buf1 (6 units each); wait kt0 landed
    STAGE_A2(lds,         0); STAGE_B4(lds + 49152, 0);
    STAGE_A2(lds + 16384, 1); STAGE_B4(lds + 81920, 1);
    asm volatile("s_waitcnt vmcnt(6)" ::: "memory");
    BAR();

    int cb = 0;
    for (int kt = 0; kt < nkt; ++kt) {
        char* cA = lds + cb*16384;
        char* cB = lds + 49152 + cb*32768;
        int sb = cb + 2; if (sb >= 3) sb -= 3;
        char* sA = lds + sb*16384;
        char* sB = lds + 49152 + sb*32768;
        const bool st = (kt + 2 < nkt);
        // single phase: 16 ds_read + 6 stage units + 32 MFMA + vmcnt + BAR
        LDA(cA); LDB(cB);
        if (st) { STAGE_A2(sA, kt+2); STAGE_B4(sB, kt+2); }
        MMQ_ALL();
        if (st)                { asm volatile("s_waitcnt vmcnt(6)" ::: "memory"); }
        else if (kt == nkt-2)  { asm volatile("s_waitcnt vmcnt(0)" ::: "memory"); }
        BAR();
        cb = cb + 1; if (cb == 3) cb = 0;
    }

    // epilogue: 16x16 C/D: col = lane&15, row = (lane>>4)*4 + q
    float* outp = out + (size_t)job * BFR;
#pragma unroll
    for (int mi = 0; mi < 4; ++mi) {
        const int gm0 = mt*128 + wm*64 + mi*16 + lk*4;
#pragma unroll
        for (int j = 0; j < 4; ++j) {
            const int gn = nt*256 + wn*64 + j*16 + lr;
            if (gn < Rdim) {
                const float rr = (job == 2) ? root_role[gn] : 0.f;
#pragma unroll
                for (int q = 0; q < 4; ++q) {
                    const int gm = gm0 + q;
                    float v = acc[mi][j][q];
                    if (job == 2) v += root_filler[gm] * rr;
                    outp[(size_t)gm*Rdim + gn] = v;
                }
            }
        }
    }
}

// ---------------------------------------------------------------------------
extern "C" void kernel_launch(void* const* d_in, const int* in_sizes, int n_in,
                              void* d_out, int out_size, void* d_ws, size_t ws_size,
                              hipStream_t stream)
{
    const float* x           = (const float*)d_in[0];
    const float* car_w       = (const float*)d_in[1];
    const float* cdr_w       = (const float*)d_in[2];
    const float* cons1_w     = (const float*)d_in[3];
    const float* cons2_w     = (const float*)d_in[4];
    const float* root_filler = (const float*)d_in[5];
    const float* Dl          = (const float*)d_in[6];
    const float* Dr          = (const float*)d_in[7];
    const float* El          = (const float*)d_in[8];
    const float* Er          = (const float*)d_in[9];
    const float* root_role   = (const float*)d_in[10];
    float* out = (float*)d_out;

    bf16* args = (bf16*)d_ws;                 // 33.5 MB
    bf16* dpad = args + 16777216;             //  8.4 MB

    k_prep  <<<dim3(6145), dim3(256), 0, stream>>>(
        x, car_w, cdr_w, cons1_w, cons2_w, Dl, Dr, El, Er, args, dpad, out);
    k_gemm1p<<<dim3(384),  dim3(512), 0, stream>>>(
        args, dpad, root_filler, root_role, out);
}